// Round 2
// baseline (1016.169 us; speedup 1.0000x reference)
//
#include <hip/hip_runtime.h>
#include <hip/hip_bf16.h>

#define NTOK 4096   // B*S tokens
#define HD   1024   // hidden
#define ID   4096   // intermediate
#define NE   8      // experts
#define LDH  (NE * ID)   // 32768: hmid leading dim (all experts side by side)

typedef float  floatx4 __attribute__((ext_vector_type(4)));
typedef __bf16 bf16x8  __attribute__((ext_vector_type(8)));
typedef unsigned short u16;

__device__ __forceinline__ u16 f2bf(float f) {
    union { float f; unsigned int i; } c; c.f = f;
    return (u16)((c.i + 0x7fffu + ((c.i >> 16) & 1u)) >> 16);   // RNE
}

// async global->LDS, 16B per lane; lds must be the wave-uniform chunk base
__device__ __forceinline__ void async_copy16(u16* lds, const u16* g) {
    __builtin_amdgcn_global_load_lds(
        (const __attribute__((address_space(1))) void*)g,
        (__attribute__((address_space(3))) void*)lds, 16, 0, 0);
}

// tanh-approx GELU (max abs err ~3e-3)
__device__ __forceinline__ float gelu_fast(float v) {
    const float u = v * (0.7978845608f + 0.0356774081f * v * v);
    const float t = 1.f - 2.f / (__expf(2.f * u) + 1.f);
    return 0.5f * v * (1.f + t);
}

// scheduling fences: raw barrier (no implicit vmcnt drain) + counted waits
#define FENCE()  asm volatile("" ::: "memory")
#define BAR()    do { FENCE(); __builtin_amdgcn_s_barrier(); FENCE(); } while (0)
#define WAITV8() asm volatile("s_waitcnt vmcnt(8)" ::: "memory")
#define WAITV4() asm volatile("s_waitcnt vmcnt(4)" ::: "memory")
#define WAITV0() asm volatile("s_waitcnt vmcnt(0)" ::: "memory")
#define WAITL0() asm volatile("s_waitcnt lgkmcnt(0)" ::: "memory")

// ---------------- fp32 -> bf16 conversion (8 elems/thread) ----------------
__global__ __launch_bounds__(256) void convert_kernel(
    const float* __restrict__ src, u16* __restrict__ dst)
{
    const size_t i = ((size_t)blockIdx.x * 256 + threadIdx.x) * 8;
    const float4 a = *(const float4*)(src + i);
    const float4 b = *(const float4*)(src + i + 4);
    ushort4 o0, o1;
    o0.x = f2bf(a.x); o0.y = f2bf(a.y); o0.z = f2bf(a.z); o0.w = f2bf(a.w);
    o1.x = f2bf(b.x); o1.y = f2bf(b.y); o1.z = f2bf(b.z); o1.w = f2bf(b.w);
    *(ushort4*)(dst + i)     = o0;
    *(ushort4*)(dst + i + 4) = o1;
}

// ---------------- router: logits -> softmax -> sort desc -> w[rank][n] ----
__global__ __launch_bounds__(256) void router_kernel(
    const float* __restrict__ x, const float* __restrict__ Wr,
    float* __restrict__ wbuf)
{
    const int n    = blockIdx.x * 4 + (threadIdx.x >> 6);
    const int lane = threadIdx.x & 63;
    const float* xr = x + (size_t)n * HD;
    float acc[NE];
#pragma unroll
    for (int e = 0; e < NE; ++e) acc[e] = 0.f;
    for (int h = lane; h < HD; h += 64) {
        const float xv = xr[h];
#pragma unroll
        for (int e = 0; e < NE; ++e) acc[e] += xv * Wr[e * HD + h];
    }
#pragma unroll
    for (int e = 0; e < NE; ++e) {
        float v = acc[e];
#pragma unroll
        for (int off = 32; off > 0; off >>= 1) v += __shfl_xor(v, off, 64);
        acc[e] = v;
    }
    float mx = acc[0];
#pragma unroll
    for (int e = 1; e < NE; ++e) mx = fmaxf(mx, acc[e]);
    float s = 0.f;
#pragma unroll
    for (int e = 0; e < NE; ++e) { acc[e] = __expf(acc[e] - mx); s += acc[e]; }
    const float inv = 1.f / s;
#pragma unroll
    for (int e = 0; e < NE; ++e) acc[e] *= inv;
#pragma unroll
    for (int i = 0; i < NE - 1; ++i)
#pragma unroll
        for (int j = 0; j < NE - 1 - i; ++j) {
            const float a = acc[j], b = acc[j + 1];
            acc[j] = fmaxf(a, b); acc[j + 1] = fminf(a, b);
        }
    if (lane < NE) wbuf[lane * NTOK + n] = acc[lane];
}

// ======= 256x256 / BK=32 / 4-deep LDS ring / 2x16-MFMA phases per tile =====
// A: row-major (M x ldA); B: row-major (N x ldB) i.e. B^T input.
// Per K-tile t (buf = t&3), stage target = buf (t+3)&3 (freed at end of t-1):
//   P1: ds_read A0-3,B0-3 (8) | stage half0 of t+3 (2 gload_lds) | bar |
//       16 MFMA (mi0-3, compiler-scheduled lgkmcnt) | bar
//   P2: ds_read A4-7 (4)      | stage half1 of t+3 (2 gload_lds) | bar |
//       16 MFMA (mi4-7) | lgkm(0) | vmcnt(8) | bar
// Invariants: vmcnt(8) before tile-final bar <=> tile t+1's 4 loads landed
// (FIFO, 4 loads/tile); lgkm(0) before tile-final bar <=> all our ds_reads
// of buf t&3 done before anyone stages into it (at t+1, target (t+4)&3=t&3).
__device__ __forceinline__ void gemm256_tile(
    const u16* __restrict__ A, const u16* __restrict__ B,
    int ldA, int ldB, int nkt, int rowBase, int colBase,
    u16* As, u16* Bs, floatx4 acc[8][4])
{
    const int tid  = threadIdx.x;        // 0..511
    const int w    = tid >> 6, lane = tid & 63;
    const int wm   = w & 1, wn = w >> 1; // wave tile: rows wm*128, cols wn*64
    const int quad = lane >> 4, l15 = lane & 15;

    // staging: wave w stages rows [h*128 + w*16, +16); source column
    // pre-swizzled so linear global_load_lds lands the swizzled layout
    // (chunk c at (row,c) holds logical c ^ ((row>>1)&3))
    const int srow   = (w << 4) + (lane >> 2);                    // 0..127
    const int schunk = ((lane & 3) ^ ((lane >> 3) & 3)) << 3;     // elems
    const u16* gA = A + (size_t)(rowBase + srow) * ldA + schunk;
    const u16* gB = B + (size_t)(colBase + srow) * ldB + schunk;
    const size_t hA = (size_t)128 * ldA, hB = (size_t)128 * ldB;
    const int wofs = w << 9;             // wave-uniform 1KB chunk base (elems)

    // frag read offsets (swizzle-matched): 2-way bank aliasing = free
    const int sw = (l15 >> 1) & 3;
    int aoff[8], boff[4];
#pragma unroll
    for (int mi = 0; mi < 8; ++mi)
        aoff[mi] = (wm * 128 + mi * 16 + l15) * 32 + ((quad ^ sw) << 3);
#pragma unroll
    for (int ni = 0; ni < 4; ++ni)
        boff[ni] = (wn * 64 + ni * 16 + l15) * 32 + ((quad ^ sw) << 3);

    // prologue: stage tiles 0,1,2 (12 loads); vmcnt(8) => tile 0 landed
#pragma unroll
    for (int pt = 0; pt < 3; ++pt) {
        const int ko = pt << 5;
        u16* lA = As + pt * 8192 + wofs;
        u16* lB = Bs + pt * 8192 + wofs;
        async_copy16(lA,        gA + ko);
        async_copy16(lA + 4096, gA + ko + hA);
        async_copy16(lB,        gB + ko);
        async_copy16(lB + 4096, gB + ko + hB);
    }
    WAITV8(); BAR();

    bf16x8 af[8], bfr[4];
#pragma unroll 1
    for (int t = 0; t < nkt; ++t) {
        const u16* Ab = As + (t & 3) * 8192;
        const u16* Bb = Bs + (t & 3) * 8192;
        const int ts = t + 3;
        u16* sA = As + (ts & 3) * 8192 + wofs;
        u16* sB = Bs + (ts & 3) * 8192 + wofs;
        const int ko = ts << 5;
        // ---- phase 1: quad mi0-3 ----
#pragma unroll
        for (int mi = 0; mi < 4; ++mi) af[mi] = *(const bf16x8*)(Ab + aoff[mi]);
#pragma unroll
        for (int ni = 0; ni < 4; ++ni) bfr[ni] = *(const bf16x8*)(Bb + boff[ni]);
        if (ts < nkt) {
            async_copy16(sA, gA + ko);
            async_copy16(sB, gB + ko);
        }
        BAR();
        __builtin_amdgcn_s_setprio(1);
#pragma unroll
        for (int mi = 0; mi < 4; ++mi)
#pragma unroll
            for (int ni = 0; ni < 4; ++ni)
                acc[mi][ni] = __builtin_amdgcn_mfma_f32_16x16x32_bf16(
                    af[mi], bfr[ni], acc[mi][ni], 0, 0, 0);
        __builtin_amdgcn_s_setprio(0);
        BAR();
        // ---- phase 2: quad mi4-7 ----
#pragma unroll
        for (int mi = 4; mi < 8; ++mi) af[mi] = *(const bf16x8*)(Ab + aoff[mi]);
        if (ts < nkt) {
            async_copy16(sA + 4096, gA + ko + hA);
            async_copy16(sB + 4096, gB + ko + hB);
        }
        BAR();
        __builtin_amdgcn_s_setprio(1);
#pragma unroll
        for (int mi = 4; mi < 8; ++mi)
#pragma unroll
            for (int ni = 0; ni < 4; ++ni)
                acc[mi][ni] = __builtin_amdgcn_mfma_f32_16x16x32_bf16(
                    af[mi], bfr[ni], acc[mi][ni], 0, 0, 0);
        __builtin_amdgcn_s_setprio(0);
        WAITL0();                        // drain our buf-t reads pre-publish
        if (t + 4 <= nkt)      { WAITV8(); }   // {t+1,t+2,t+3} stay in flight
        else if (t + 3 <= nkt) { WAITV4(); }   // tail: {t+2} in flight
        else                   { WAITV0(); }   // last tiles: drain
        BAR();
    }
}

// ------- GEMM1 (all experts): hmid[n, e*I+i] = w[e][n]*gelu(X @ W1^T) -----
__global__ __launch_bounds__(512, 2) void gemm1_kernel(
    const u16* __restrict__ X, const u16* __restrict__ W1b,
    const float* __restrict__ wbuf, u16* __restrict__ hmid)
{
    __shared__ __align__(16) u16 As[4][8192];   // 4-deep ring, 64 KB
    __shared__ __align__(16) u16 Bs[4][8192];   // total 128 KB
    floatx4 acc[8][4] = {};
    // XCD-bijective swizzle (2048 % 8 == 0): XCD x gets mt in {2x,2x+1},
    // all 128 nt -> A row-panel stays in its L2 while B streams.
    const int bid = blockIdx.x;
    const int swz = (bid & 7) * 256 + (bid >> 3);
    const int mt = swz >> 7, nt = swz & 127;
    const int rowBase = mt * 256, colBase = nt * 256;
    const int e = colBase >> 12;                // 256-col tile within one expert

    gemm256_tile(X, W1b, HD, HD, HD / 32, rowBase, colBase,
                 &As[0][0], &Bs[0][0], acc);

    const int t = threadIdx.x, w = t >> 6, lane = t & 63;
    const int wm = w & 1, wn = w >> 1, quad = lane >> 4, l15 = lane & 15;
#pragma unroll
    for (int mi = 0; mi < 8; ++mi)
#pragma unroll
        for (int r = 0; r < 4; ++r) {
            const int row = rowBase + wm * 128 + mi * 16 + quad * 4 + r;
            const float wv = wbuf[e * NTOK + row];
#pragma unroll
            for (int ni = 0; ni < 4; ++ni) {
                const int col = colBase + wn * 64 + ni * 16 + l15;
                hmid[(size_t)row * LDH + col] =
                    f2bf(gelu_fast(acc[mi][ni][r]) * wv);
            }
        }
}

// ------- GEMM2 (expert-pair per z): slice[z] = sum_e hmid_e @ W2_e^T ------
__global__ __launch_bounds__(512, 2) void gemm2_kernel(
    const u16* __restrict__ hmid, const u16* __restrict__ W2b,
    float* __restrict__ accbuf)
{
    __shared__ __align__(16) u16 As[4][8192];
    __shared__ __align__(16) u16 Bs[4][8192];
    floatx4 acc[8][4] = {};
    // 256 blocks (256 % 8 == 0): XCD x -> one z-pair + mt chunk; the 4
    // nt-blocks of one mt run on one XCD -> hmid row-panel L2 reuse
    const int bid = blockIdx.x;
    const int swz = (bid & 7) * 32 + (bid >> 3);
    const int z = swz >> 6, mt = (swz >> 2) & 15, nt = swz & 3;
    const int rowBase = mt * 256, colBase = nt * 256;

    for (int ee = 0; ee < 2; ++ee) {
        const int e = 2 * z + ee;
        gemm256_tile(hmid + (size_t)e * ID, W2b + (size_t)e * HD * ID,
                     LDH, ID, ID / 32, rowBase, colBase,
                     &As[0][0], &Bs[0][0], acc);
    }

    float* accs = accbuf + (size_t)z * NTOK * HD;
    const int t = threadIdx.x, w = t >> 6, lane = t & 63;
    const int wm = w & 1, wn = w >> 1, quad = lane >> 4, l15 = lane & 15;
#pragma unroll
    for (int mi = 0; mi < 8; ++mi)
#pragma unroll
        for (int r = 0; r < 4; ++r) {
            const int row = rowBase + wm * 128 + mi * 16 + quad * 4 + r;
#pragma unroll
            for (int ni = 0; ni < 4; ++ni) {
                const int col = colBase + wn * 64 + ni * 16 + l15;
                accs[(size_t)row * HD + col] = acc[mi][ni][r];
            }
        }
}

// ---------------- finalize: out = sum of 4 slices (fp32) ------------------
__global__ __launch_bounds__(256) void finalize_kernel(
    const float* __restrict__ accbuf, float* __restrict__ out)
{
    const size_t NH = (size_t)NTOK * HD;
    const size_t i = ((size_t)blockIdx.x * 256 + threadIdx.x) * 4;
    const float4 a = *(const float4*)(accbuf + i);
    const float4 b = *(const float4*)(accbuf + NH + i);
    const float4 c = *(const float4*)(accbuf + 2 * NH + i);
    const float4 d = *(const float4*)(accbuf + 3 * NH + i);
    float4 o;
    o.x = a.x + b.x + c.x + d.x; o.y = a.y + b.y + c.y + d.y;
    o.z = a.z + b.z + c.z + d.z; o.w = a.w + b.w + c.w + d.w;
    *(float4*)(out + i) = o;
}

extern "C" void kernel_launch(void* const* d_in, const int* in_sizes, int n_in,
                              void* d_out, int out_size, void* d_ws, size_t ws_size,
                              hipStream_t stream) {
    const float* x  = (const float*)d_in[0];   // (N, H) fp32
    const float* Wr = (const float*)d_in[1];   // (E, H) fp32
    const float* W1 = (const float*)d_in[2];   // (E, I, H) fp32
    const float* W2 = (const float*)d_in[3];   // (E, H, I) fp32
    float* out = (float*)d_out;                // (N, H) fp32

    const size_t MB = 1024 * 1024;
    char* ws = (char*)d_ws;
    float* wbuf   = (float*)ws;
    u16*   Xb     = (u16*)(ws + 131072);
    u16*   W1b    = (u16*)(ws + 131072 + 8 * MB);
    u16*   W2b    = (u16*)(ws + 131072 + 72 * MB);
    u16*   hmid   = (u16*)(ws + 131072 + 136 * MB);
    float* accbuf = (float*)(ws + 131072 + 392 * MB);
    if (ws_size < 131072 + 456 * MB) return;

    convert_kernel<<<dim3((NTOK * HD) / 2048), 256, 0, stream>>>(x, Xb);
    convert_kernel<<<dim3((NE * ID * HD) / 2048), 256, 0, stream>>>(W1, W1b);
    convert_kernel<<<dim3((NE * HD * ID) / 2048), 256, 0, stream>>>(W2, W2b);
    router_kernel<<<dim3(NTOK / 4), 256, 0, stream>>>(x, Wr, wbuf);

    gemm1_kernel<<<dim3(NE * ID / 256 * (NTOK / 256)), 512, 0, stream>>>(
        Xb, W1b, wbuf, hmid);
    gemm2_kernel<<<dim3((NTOK / 256) * (HD / 256) * 4), 512, 0, stream>>>(
        hmid, W2b, accbuf);
    finalize_kernel<<<dim3(NTOK * HD / 1024), 256, 0, stream>>>(accbuf, out);
}

// Round 3
// 1013.929 us; speedup vs baseline: 1.0022x; 1.0022x over previous
//
#include <hip/hip_runtime.h>
#include <hip/hip_bf16.h>

#define NTOK 4096   // B*S tokens
#define HD   1024   // hidden
#define ID   4096   // intermediate
#define NE   8      // experts
#define LDH  (NE * ID)   // 32768: hmid leading dim (all experts side by side)

typedef float  floatx4 __attribute__((ext_vector_type(4)));
typedef __bf16 bf16x8  __attribute__((ext_vector_type(8)));
typedef unsigned short u16;

__device__ __forceinline__ u16 f2bf(float f) {
    union { float f; unsigned int i; } c; c.f = f;
    return (u16)((c.i + 0x7fffu + ((c.i >> 16) & 1u)) >> 16);   // RNE
}

// async global->LDS, 16B per lane; lds must be the wave-uniform chunk base
__device__ __forceinline__ void async_copy16(u16* lds, const u16* g) {
    __builtin_amdgcn_global_load_lds(
        (const __attribute__((address_space(1))) void*)g,
        (__attribute__((address_space(3))) void*)lds, 16, 0, 0);
}

// tanh-approx GELU (max abs err ~3e-3)
__device__ __forceinline__ float gelu_fast(float v) {
    const float u = v * (0.7978845608f + 0.0356774081f * v * v);
    const float t = 1.f - 2.f / (__expf(2.f * u) + 1.f);
    return 0.5f * v * (1.f + t);
}

// scheduling fences: raw barrier (no implicit vmcnt drain) + counted waits
#define FENCE()  asm volatile("" ::: "memory")
#define BAR()    do { FENCE(); __builtin_amdgcn_s_barrier(); FENCE(); } while (0)
#define WAITV4() asm volatile("s_waitcnt vmcnt(4)" ::: "memory")
#define WAITV0() asm volatile("s_waitcnt vmcnt(0)" ::: "memory")
#define WAITL0() asm volatile("s_waitcnt lgkmcnt(0)" ::: "memory")

// ---------------- fp32 -> bf16 conversion (8 elems/thread) ----------------
__global__ __launch_bounds__(256) void convert_kernel(
    const float* __restrict__ src, u16* __restrict__ dst)
{
    const size_t i = ((size_t)blockIdx.x * 256 + threadIdx.x) * 8;
    const float4 a = *(const float4*)(src + i);
    const float4 b = *(const float4*)(src + i + 4);
    ushort4 o0, o1;
    o0.x = f2bf(a.x); o0.y = f2bf(a.y); o0.z = f2bf(a.z); o0.w = f2bf(a.w);
    o1.x = f2bf(b.x); o1.y = f2bf(b.y); o1.z = f2bf(b.z); o1.w = f2bf(b.w);
    *(ushort4*)(dst + i)     = o0;
    *(ushort4*)(dst + i + 4) = o1;
}

// same, two sources in one launch (W1 + W2): saves a dispatch gap
__global__ __launch_bounds__(256) void convert2_kernel(
    const float* __restrict__ s1, u16* __restrict__ d1,
    const float* __restrict__ s2, u16* __restrict__ d2, int half)
{
    const int b = blockIdx.x;
    const float* src = (b < half) ? s1 : s2;
    u16*         dst = (b < half) ? d1 : d2;
    const int    bb  = (b < half) ? b : b - half;
    const size_t i = ((size_t)bb * 256 + threadIdx.x) * 8;
    const float4 a = *(const float4*)(src + i);
    const float4 c = *(const float4*)(src + i + 4);
    ushort4 o0, o1;
    o0.x = f2bf(a.x); o0.y = f2bf(a.y); o0.z = f2bf(a.z); o0.w = f2bf(a.w);
    o1.x = f2bf(c.x); o1.y = f2bf(c.y); o1.z = f2bf(c.z); o1.w = f2bf(c.w);
    *(ushort4*)(dst + i)     = o0;
    *(ushort4*)(dst + i + 4) = o1;
}

// ---------------- router: logits -> softmax -> sort desc -> w[rank][n] ----
__global__ __launch_bounds__(256) void router_kernel(
    const float* __restrict__ x, const float* __restrict__ Wr,
    float* __restrict__ wbuf)
{
    const int n    = blockIdx.x * 4 + (threadIdx.x >> 6);
    const int lane = threadIdx.x & 63;
    const float* xr = x + (size_t)n * HD;
    float acc[NE];
#pragma unroll
    for (int e = 0; e < NE; ++e) acc[e] = 0.f;
    for (int h = lane; h < HD; h += 64) {
        const float xv = xr[h];
#pragma unroll
        for (int e = 0; e < NE; ++e) acc[e] += xv * Wr[e * HD + h];
    }
#pragma unroll
    for (int e = 0; e < NE; ++e) {
        float v = acc[e];
#pragma unroll
        for (int off = 32; off > 0; off >>= 1) v += __shfl_xor(v, off, 64);
        acc[e] = v;
    }
    float mx = acc[0];
#pragma unroll
    for (int e = 1; e < NE; ++e) mx = fmaxf(mx, acc[e]);
    float s = 0.f;
#pragma unroll
    for (int e = 0; e < NE; ++e) { acc[e] = __expf(acc[e] - mx); s += acc[e]; }
    const float inv = 1.f / s;
#pragma unroll
    for (int e = 0; e < NE; ++e) acc[e] *= inv;
#pragma unroll
    for (int i = 0; i < NE - 1; ++i)
#pragma unroll
        for (int j = 0; j < NE - 1 - i; ++j) {
            const float a = acc[j], b = acc[j + 1];
            acc[j] = fmaxf(a, b); acc[j + 1] = fminf(a, b);
        }
    if (lane < NE) wbuf[lane * NTOK + n] = acc[lane];
}

// ================= 256x256 / BK=32 / 8-wave phase-pipelined GEMM ==========
// Round-1 proven skeleton (2 buffers, 2 barriers/tile, vmcnt(4) counted),
// round-3 deltas: B-frag reads issued FIRST (first MFMA's operands land
// after 5 of 12 reads -> compiler's fine-grained lgkmcnt starts MFMA early)
// and the explicit lgkmcnt(0) moved AFTER the mi0-3 cluster (still before
// the release-barrier: af4-7 reads must drain before other waves stage
// over this buffer).
__device__ __forceinline__ void gemm256_tile(
    const u16* __restrict__ A, const u16* __restrict__ B,
    int ldA, int ldB, int K, int rowBase, int colBase,
    u16* As0, u16* As1, u16* Bs0, u16* Bs1,
    floatx4 acc[8][4])
{
    const int t    = threadIdx.x;        // 0..511
    const int w    = t >> 6, lane = t & 63;
    const int wm   = w & 1, wn = w >> 1; // wave tile: rows wm*128, cols wn*64
    const int quad = lane >> 4, l15 = lane & 15;

    // staging: wave w stages rows [h*128 + w*16, +16) of each half h;
    // source column pre-swizzled so linear global_load_lds produces the
    // swizzled LDS layout: chunk c at (row,c) holds logical c^((row>>1)&3)
    const int srow   = (w << 4) + (lane >> 2);                    // 0..127
    const int schunk = ((lane & 3) ^ ((lane >> 3) & 3)) << 3;     // elems
    const u16* gA = A + (size_t)(rowBase + srow) * ldA + schunk;
    const u16* gB = B + (size_t)(colBase + srow) * ldB + schunk;
    const size_t hA = (size_t)128 * ldA, hB = (size_t)128 * ldB;
    u16* lA0 = As0 + w * 512;            // wave-uniform 1KB chunk bases
    u16* lA1 = As1 + w * 512;
    u16* lB0 = Bs0 + w * 512;
    u16* lB1 = Bs1 + w * 512;

    // frag read offsets (swizzle-matched): 2-way bank aliasing = free
    const int sw = (l15 >> 1) & 3;
    int aoff[8], boff[4];
#pragma unroll
    for (int mi = 0; mi < 8; ++mi)
        aoff[mi] = (wm * 128 + mi * 16 + l15) * 32 + ((quad ^ sw) << 3);
#pragma unroll
    for (int ni = 0; ni < 4; ++ni)
        boff[ni] = (wn * 64 + ni * 16 + l15) * 32 + ((quad ^ sw) << 3);

#define STAGE2(lA, lB, kt) do { const int _ko = (kt) << 5;          \
        async_copy16(lA,        gA + _ko);                          \
        async_copy16(lA + 4096, gA + _ko + hA);                     \
        async_copy16(lB,        gB + _ko);                          \
        async_copy16(lB + 4096, gB + _ko + hB); } while (0)

    const int nkt = K >> 5;              // BK=32 tiles (even for all callers)
    bf16x8 af[8], bfr[4];
    STAGE2(lA0, lB0, 0);
    STAGE2(lA1, lB1, 1);

#pragma unroll 1
    for (int kt = 0; kt < nkt; kt += 2) {
        // ---- P1: tile kt (buf0) ----
        WAITV4(); BAR();
#pragma unroll
        for (int ni = 0; ni < 4; ++ni) bfr[ni] = *(const bf16x8*)(Bs0 + boff[ni]);
#pragma unroll
        for (int mi = 0; mi < 8; ++mi) af[mi] = *(const bf16x8*)(As0 + aoff[mi]);
        __builtin_amdgcn_s_setprio(1);
#pragma unroll
        for (int mi = 0; mi < 4; ++mi)
#pragma unroll
            for (int ni = 0; ni < 4; ++ni)
                acc[mi][ni] = __builtin_amdgcn_mfma_f32_16x16x32_bf16(
                    af[mi], bfr[ni], acc[mi][ni], 0, 0, 0);
        __builtin_amdgcn_s_setprio(0);
        WAITL0();                        // af4-7 drained pre-publish
        BAR();                           // buf0 free for overwrite
        // ---- P2: prefetch kt+2 -> buf0; back half of tile kt ----
        if (kt + 2 < nkt) STAGE2(lA0, lB0, kt + 2);
        __builtin_amdgcn_s_setprio(1);
#pragma unroll
        for (int mi = 4; mi < 8; ++mi)
#pragma unroll
            for (int ni = 0; ni < 4; ++ni)
                acc[mi][ni] = __builtin_amdgcn_mfma_f32_16x16x32_bf16(
                    af[mi], bfr[ni], acc[mi][ni], 0, 0, 0);
        __builtin_amdgcn_s_setprio(0);
        // ---- P3: tile kt+1 (buf1) ----
        if (kt + 2 < nkt) { WAITV4(); } else { WAITV0(); }
        BAR();
#pragma unroll
        for (int ni = 0; ni < 4; ++ni) bfr[ni] = *(const bf16x8*)(Bs1 + boff[ni]);
#pragma unroll
        for (int mi = 0; mi < 8; ++mi) af[mi] = *(const bf16x8*)(As1 + aoff[mi]);
        __builtin_amdgcn_s_setprio(1);
#pragma unroll
        for (int mi = 0; mi < 4; ++mi)
#pragma unroll
            for (int ni = 0; ni < 4; ++ni)
                acc[mi][ni] = __builtin_amdgcn_mfma_f32_16x16x32_bf16(
                    af[mi], bfr[ni], acc[mi][ni], 0, 0, 0);
        __builtin_amdgcn_s_setprio(0);
        WAITL0();
        BAR();                           // buf1 free for overwrite
        // ---- P4: prefetch kt+3 -> buf1; back half of tile kt+1 ----
        if (kt + 3 < nkt) STAGE2(lA1, lB1, kt + 3);
        __builtin_amdgcn_s_setprio(1);
#pragma unroll
        for (int mi = 4; mi < 8; ++mi)
#pragma unroll
            for (int ni = 0; ni < 4; ++ni)
                acc[mi][ni] = __builtin_amdgcn_mfma_f32_16x16x32_bf16(
                    af[mi], bfr[ni], acc[mi][ni], 0, 0, 0);
        __builtin_amdgcn_s_setprio(0);
    }
#undef STAGE2
}

// ------- GEMM1 (all experts): hmid[n, e*I+i] = w[e][n]*gelu(X @ W1^T) -----
__global__ __launch_bounds__(512, 2) void gemm1_kernel(
    const u16* __restrict__ X, const u16* __restrict__ W1b,
    const float* __restrict__ wbuf, u16* __restrict__ hmid)
{
    __shared__ __align__(16) u16 As[2][8192];   // 2 x 256x32 bf16
    __shared__ __align__(16) u16 Bs[2][8192];   // total 64 KB -> 2 blocks/CU
    floatx4 acc[8][4] = {};
    // XCD-bijective swizzle (2048 % 8 == 0): XCD x gets mt in {2x,2x+1},
    // all 128 nt -> A row-panel stays in its L2 while B streams.
    const int bid = blockIdx.x;
    const int swz = (bid & 7) * 256 + (bid >> 3);
    const int mt = swz >> 7, nt = swz & 127;
    const int rowBase = mt * 256, colBase = nt * 256;
    const int e = colBase >> 12;                // 256-col tile within one expert

    gemm256_tile(X, W1b, HD, HD, HD, rowBase, colBase,
                 As[0], As[1], Bs[0], Bs[1], acc);

    const int t = threadIdx.x, w = t >> 6, lane = t & 63;
    const int wm = w & 1, wn = w >> 1, quad = lane >> 4, l15 = lane & 15;
#pragma unroll
    for (int mi = 0; mi < 8; ++mi)
#pragma unroll
        for (int r = 0; r < 4; ++r) {
            const int row = rowBase + wm * 128 + mi * 16 + quad * 4 + r;
            const float wv = wbuf[e * NTOK + row];
#pragma unroll
            for (int ni = 0; ni < 4; ++ni) {
                const int col = colBase + wn * 64 + ni * 16 + l15;
                hmid[(size_t)row * LDH + col] =
                    f2bf(gelu_fast(acc[mi][ni][r]) * wv);
            }
        }
}

// ------- GEMM2 (one expert per z): slice[z] = hmid_z @ W2_z^T -------------
// z=8 -> grid 512 = 2 blocks/CU (cross-block overlap, unlike z=4's 1/CU).
// Slices 0-3 alias the wbuf/Xb/W1b region (dead after gemm1); 4-7 follow hmid.
__global__ __launch_bounds__(512, 2) void gemm2_kernel(
    const u16* __restrict__ hmid, const u16* __restrict__ W2b,
    float* __restrict__ acclo, float* __restrict__ acchi)
{
    __shared__ __align__(16) u16 As[2][8192];
    __shared__ __align__(16) u16 Bs[2][8192];
    floatx4 acc[8][4] = {};
    // 512 blocks (512 % 8 == 0): XCD x -> expert z=x; the 4 nt-blocks of one
    // (z,mt) run on that XCD -> hmid row-panel L2 reuse
    const int bid = blockIdx.x;
    const int swz = (bid & 7) * 64 + (bid >> 3);
    const int z = swz >> 6, mt = (swz >> 2) & 15, nt = swz & 3;
    const int rowBase = mt * 256, colBase = nt * 256;

    gemm256_tile(hmid + (size_t)z * ID, W2b + (size_t)z * HD * ID,
                 LDH, ID, ID, rowBase, colBase,
                 As[0], As[1], Bs[0], Bs[1], acc);

    const size_t NH = (size_t)NTOK * HD;
    float* accs = (z < 4) ? (acclo + (size_t)z * NH)
                          : (acchi + (size_t)(z - 4) * NH);
    const int t = threadIdx.x, w = t >> 6, lane = t & 63;
    const int wm = w & 1, wn = w >> 1, quad = lane >> 4, l15 = lane & 15;
#pragma unroll
    for (int mi = 0; mi < 8; ++mi)
#pragma unroll
        for (int r = 0; r < 4; ++r) {
            const int row = rowBase + wm * 128 + mi * 16 + quad * 4 + r;
#pragma unroll
            for (int ni = 0; ni < 4; ++ni) {
                const int col = colBase + wn * 64 + ni * 16 + l15;
                accs[(size_t)row * HD + col] = acc[mi][ni][r];
            }
        }
}

// ---------------- finalize: out = sum of 8 slices (fp32) ------------------
__global__ __launch_bounds__(256) void finalize_kernel(
    const float* __restrict__ acclo, const float* __restrict__ acchi,
    float* __restrict__ out)
{
    const size_t NH = (size_t)NTOK * HD;
    const size_t i = ((size_t)blockIdx.x * 256 + threadIdx.x) * 4;
    float4 o = *(const float4*)(acclo + i);
#pragma unroll
    for (int z = 1; z < 4; ++z) {
        const float4 a = *(const float4*)(acclo + (size_t)z * NH + i);
        o.x += a.x; o.y += a.y; o.z += a.z; o.w += a.w;
    }
#pragma unroll
    for (int z = 0; z < 4; ++z) {
        const float4 a = *(const float4*)(acchi + (size_t)z * NH + i);
        o.x += a.x; o.y += a.y; o.z += a.z; o.w += a.w;
    }
    *(float4*)(out + i) = o;
}

extern "C" void kernel_launch(void* const* d_in, const int* in_sizes, int n_in,
                              void* d_out, int out_size, void* d_ws, size_t ws_size,
                              hipStream_t stream) {
    const float* x  = (const float*)d_in[0];   // (N, H) fp32
    const float* Wr = (const float*)d_in[1];   // (E, H) fp32
    const float* W1 = (const float*)d_in[2];   // (E, I, H) fp32
    const float* W2 = (const float*)d_in[3];   // (E, H, I) fp32
    float* out = (float*)d_out;                // (N, H) fp32

    // ws layout (bytes):
    //   wbuf   @ 0        : E*N f32   = 128 KB   } dead after gemm1 ->
    //   Xb     @ 128K     : N*H bf16  = 8 MB     } aliased by acclo
    //   W1b    @ +8M      : E*I*H bf16= 64 MB    } (slices 0-3, 64 MB)
    //   W2b    @ 72.125M  : E*H*I bf16= 64 MB
    //   hmid   @ 136.125M : N*E*I bf16= 256 MB
    //   acchi  @ 392.125M : 4*N*H f32 = 64 MB  (slices 4-7)
    const size_t MB = 1024 * 1024;
    char* ws = (char*)d_ws;
    float* wbuf   = (float*)ws;
    u16*   Xb     = (u16*)(ws + 131072);
    u16*   W1b    = (u16*)(ws + 131072 + 8 * MB);
    u16*   W2b    = (u16*)(ws + 131072 + 72 * MB);
    u16*   hmid   = (u16*)(ws + 131072 + 136 * MB);
    float* acclo  = (float*)ws;                       // aliases wbuf/Xb/W1b
    float* acchi  = (float*)(ws + 131072 + 392 * MB);
    if (ws_size < 131072 + 456 * MB) return;   // fail loudly rather than corrupt

    convert_kernel<<<dim3((NTOK * HD) / 2048), 256, 0, stream>>>(x, Xb);
    convert2_kernel<<<dim3(2 * (NE * ID * HD) / 2048), 256, 0, stream>>>(
        W1, W1b, W2, W2b, (NE * ID * HD) / 2048);
    router_kernel<<<dim3(NTOK / 4), 256, 0, stream>>>(x, Wr, wbuf);

    gemm1_kernel<<<dim3(NE * ID / 256 * (NTOK / 256)), 512, 0, stream>>>(
        Xb, W1b, wbuf, hmid);
    gemm2_kernel<<<dim3((NTOK / 256) * (HD / 256) * 8), 512, 0, stream>>>(
        hmid, W2b, acclo, acchi);
    finalize_kernel<<<dim3(NTOK * HD / 1024), 256, 0, stream>>>(
        acclo, acchi, out);
}

// Round 4
// 946.312 us; speedup vs baseline: 1.0738x; 1.0715x over previous
//
#include <hip/hip_runtime.h>
#include <hip/hip_bf16.h>

#define NTOK 4096   // B*S tokens
#define HD   1024   // hidden
#define ID   4096   // intermediate
#define NE   8      // experts

typedef float  floatx4 __attribute__((ext_vector_type(4)));
typedef __bf16 bf16x8  __attribute__((ext_vector_type(8)));
typedef unsigned short u16;

__device__ __forceinline__ u16 f2bf(float f) {
    union { float f; unsigned int i; } c; c.f = f;
    return (u16)((c.i + 0x7fffu + ((c.i >> 16) & 1u)) >> 16);   // RNE
}

// async global->LDS, 16B per lane; lds must be the wave-uniform chunk base
__device__ __forceinline__ void async_copy16(u16* lds, const u16* g) {
    __builtin_amdgcn_global_load_lds(
        (const __attribute__((address_space(1))) void*)g,
        (__attribute__((address_space(3))) void*)lds, 16, 0, 0);
}

// tanh-approx GELU (max abs err ~3e-3)
__device__ __forceinline__ float gelu_fast(float v) {
    const float u = v * (0.7978845608f + 0.0356774081f * v * v);
    const float t = 1.f - 2.f / (__expf(2.f * u) + 1.f);
    return 0.5f * v * (1.f + t);
}

// scheduling fences: raw barrier (no implicit vmcnt drain) + counted waits
#define FENCE()  asm volatile("" ::: "memory")
#define BAR()    do { FENCE(); __builtin_amdgcn_s_barrier(); FENCE(); } while (0)
#define WAITV4() asm volatile("s_waitcnt vmcnt(4)" ::: "memory")
#define WAITV0() asm volatile("s_waitcnt vmcnt(0)" ::: "memory")
#define WAITL0() asm volatile("s_waitcnt lgkmcnt(0)" ::: "memory")

// ---------------- fp32 -> bf16 conversion (8 elems/thread) ----------------
__global__ __launch_bounds__(256) void convert_kernel(
    const float* __restrict__ src, u16* __restrict__ dst)
{
    const size_t i = ((size_t)blockIdx.x * 256 + threadIdx.x) * 8;
    const float4 a = *(const float4*)(src + i);
    const float4 b = *(const float4*)(src + i + 4);
    ushort4 o0, o1;
    o0.x = f2bf(a.x); o0.y = f2bf(a.y); o0.z = f2bf(a.z); o0.w = f2bf(a.w);
    o1.x = f2bf(b.x); o1.y = f2bf(b.y); o1.z = f2bf(b.z); o1.w = f2bf(b.w);
    *(ushort4*)(dst + i)     = o0;
    *(ushort4*)(dst + i + 4) = o1;
}

// same, two sources in one launch (W1 + W2): saves a dispatch gap
__global__ __launch_bounds__(256) void convert2_kernel(
    const float* __restrict__ s1, u16* __restrict__ d1,
    const float* __restrict__ s2, u16* __restrict__ d2, int half)
{
    const int b = blockIdx.x;
    const float* src = (b < half) ? s1 : s2;
    u16*         dst = (b < half) ? d1 : d2;
    const int    bb  = (b < half) ? b : b - half;
    const size_t i = ((size_t)bb * 256 + threadIdx.x) * 8;
    const float4 a = *(const float4*)(src + i);
    const float4 c = *(const float4*)(src + i + 4);
    ushort4 o0, o1;
    o0.x = f2bf(a.x); o0.y = f2bf(a.y); o0.z = f2bf(a.z); o0.w = f2bf(a.w);
    o1.x = f2bf(c.x); o1.y = f2bf(c.y); o1.z = f2bf(c.z); o1.w = f2bf(c.w);
    *(ushort4*)(dst + i)     = o0;
    *(ushort4*)(dst + i + 4) = o1;
}

// ---------------- router: logits -> softmax -> sort desc -> w[rank][n] ----
__global__ __launch_bounds__(256) void router_kernel(
    const float* __restrict__ x, const float* __restrict__ Wr,
    float* __restrict__ wbuf)
{
    const int n    = blockIdx.x * 4 + (threadIdx.x >> 6);
    const int lane = threadIdx.x & 63;
    const float* xr = x + (size_t)n * HD;
    float acc[NE];
#pragma unroll
    for (int e = 0; e < NE; ++e) acc[e] = 0.f;
    for (int h = lane; h < HD; h += 64) {
        const float xv = xr[h];
#pragma unroll
        for (int e = 0; e < NE; ++e) acc[e] += xv * Wr[e * HD + h];
    }
#pragma unroll
    for (int e = 0; e < NE; ++e) {
        float v = acc[e];
#pragma unroll
        for (int off = 32; off > 0; off >>= 1) v += __shfl_xor(v, off, 64);
        acc[e] = v;
    }
    float mx = acc[0];
#pragma unroll
    for (int e = 1; e < NE; ++e) mx = fmaxf(mx, acc[e]);
    float s = 0.f;
#pragma unroll
    for (int e = 0; e < NE; ++e) { acc[e] = __expf(acc[e] - mx); s += acc[e]; }
    const float inv = 1.f / s;
#pragma unroll
    for (int e = 0; e < NE; ++e) acc[e] *= inv;
#pragma unroll
    for (int i = 0; i < NE - 1; ++i)
#pragma unroll
        for (int j = 0; j < NE - 1 - i; ++j) {
            const float a = acc[j], b = acc[j + 1];
            acc[j] = fmaxf(a, b); acc[j + 1] = fminf(a, b);
        }
    if (lane < NE) wbuf[lane * NTOK + n] = acc[lane];
}

// ================= 256x256 / BK=32 / 8-wave phase-pipelined GEMM ==========
// Proven round-1 skeleton (2 buffers, 2 barriers/tile, vmcnt(4) counted,
// swizzled LDS -> 0 bank conflicts). Unchanged this round.
__device__ __forceinline__ void gemm256_tile(
    const u16* __restrict__ A, const u16* __restrict__ B,
    int ldA, int ldB, int K, int rowBase, int colBase,
    u16* As0, u16* As1, u16* Bs0, u16* Bs1,
    floatx4 acc[8][4])
{
    const int t    = threadIdx.x;        // 0..511
    const int w    = t >> 6, lane = t & 63;
    const int wm   = w & 1, wn = w >> 1; // wave tile: rows wm*128, cols wn*64
    const int quad = lane >> 4, l15 = lane & 15;

    // staging: wave w stages rows [h*128 + w*16, +16) of each half h;
    // source column pre-swizzled so linear global_load_lds produces the
    // swizzled LDS layout: chunk c at (row,c) holds logical c^((row>>1)&3)
    const int srow   = (w << 4) + (lane >> 2);                    // 0..127
    const int schunk = ((lane & 3) ^ ((lane >> 3) & 3)) << 3;     // elems
    const u16* gA = A + (size_t)(rowBase + srow) * ldA + schunk;
    const u16* gB = B + (size_t)(colBase + srow) * ldB + schunk;
    const size_t hA = (size_t)128 * ldA, hB = (size_t)128 * ldB;
    u16* lA0 = As0 + w * 512;            // wave-uniform 1KB chunk bases
    u16* lA1 = As1 + w * 512;
    u16* lB0 = Bs0 + w * 512;
    u16* lB1 = Bs1 + w * 512;

    // frag read offsets (swizzle-matched): 2-way bank aliasing = free
    const int sw = (l15 >> 1) & 3;
    int aoff[8], boff[4];
#pragma unroll
    for (int mi = 0; mi < 8; ++mi)
        aoff[mi] = (wm * 128 + mi * 16 + l15) * 32 + ((quad ^ sw) << 3);
#pragma unroll
    for (int ni = 0; ni < 4; ++ni)
        boff[ni] = (wn * 64 + ni * 16 + l15) * 32 + ((quad ^ sw) << 3);

#define STAGE2(lA, lB, kt) do { const int _ko = (kt) << 5;          \
        async_copy16(lA,        gA + _ko);                          \
        async_copy16(lA + 4096, gA + _ko + hA);                     \
        async_copy16(lB,        gB + _ko);                          \
        async_copy16(lB + 4096, gB + _ko + hB); } while (0)

    const int nkt = K >> 5;              // BK=32 tiles (even for all callers)
    bf16x8 af[8], bfr[4];
    STAGE2(lA0, lB0, 0);
    STAGE2(lA1, lB1, 1);

#pragma unroll 1
    for (int kt = 0; kt < nkt; kt += 2) {
        // ---- P1: tile kt (buf0) ----
        WAITV4(); BAR();
#pragma unroll
        for (int ni = 0; ni < 4; ++ni) bfr[ni] = *(const bf16x8*)(Bs0 + boff[ni]);
#pragma unroll
        for (int mi = 0; mi < 8; ++mi) af[mi] = *(const bf16x8*)(As0 + aoff[mi]);
        __builtin_amdgcn_s_setprio(1);
#pragma unroll
        for (int mi = 0; mi < 4; ++mi)
#pragma unroll
            for (int ni = 0; ni < 4; ++ni)
                acc[mi][ni] = __builtin_amdgcn_mfma_f32_16x16x32_bf16(
                    af[mi], bfr[ni], acc[mi][ni], 0, 0, 0);
        __builtin_amdgcn_s_setprio(0);
        WAITL0();                        // af4-7 drained pre-publish
        BAR();                           // buf0 free for overwrite
        // ---- P2: prefetch kt+2 -> buf0; back half of tile kt ----
        if (kt + 2 < nkt) STAGE2(lA0, lB0, kt + 2);
        __builtin_amdgcn_s_setprio(1);
#pragma unroll
        for (int mi = 4; mi < 8; ++mi)
#pragma unroll
            for (int ni = 0; ni < 4; ++ni)
                acc[mi][ni] = __builtin_amdgcn_mfma_f32_16x16x32_bf16(
                    af[mi], bfr[ni], acc[mi][ni], 0, 0, 0);
        __builtin_amdgcn_s_setprio(0);
        // ---- P3: tile kt+1 (buf1) ----
        if (kt + 2 < nkt) { WAITV4(); } else { WAITV0(); }
        BAR();
#pragma unroll
        for (int ni = 0; ni < 4; ++ni) bfr[ni] = *(const bf16x8*)(Bs1 + boff[ni]);
#pragma unroll
        for (int mi = 0; mi < 8; ++mi) af[mi] = *(const bf16x8*)(As1 + aoff[mi]);
        __builtin_amdgcn_s_setprio(1);
#pragma unroll
        for (int mi = 0; mi < 4; ++mi)
#pragma unroll
            for (int ni = 0; ni < 4; ++ni)
                acc[mi][ni] = __builtin_amdgcn_mfma_f32_16x16x32_bf16(
                    af[mi], bfr[ni], acc[mi][ni], 0, 0, 0);
        __builtin_amdgcn_s_setprio(0);
        WAITL0();
        BAR();                           // buf1 free for overwrite
        // ---- P4: prefetch kt+3 -> buf1; back half of tile kt+1 ----
        if (kt + 3 < nkt) STAGE2(lA1, lB1, kt + 3);
        __builtin_amdgcn_s_setprio(1);
#pragma unroll
        for (int mi = 4; mi < 8; ++mi)
#pragma unroll
            for (int ni = 0; ni < 4; ++ni)
                acc[mi][ni] = __builtin_amdgcn_mfma_f32_16x16x32_bf16(
                    af[mi], bfr[ni], acc[mi][ni], 0, 0, 0);
        __builtin_amdgcn_s_setprio(0);
    }
#undef STAGE2
}

// ------- GEMM1 (all experts): hmid[e][n][i] = w[e][n]*gelu(X @ W1_e^T) ----
// hmid layout is now expert-contiguous [E][NTOK][ID] so gemm2's A operand
// has ldA = ID (streaming locality) instead of 64KB row stride.
__global__ __launch_bounds__(512, 2) void gemm1_kernel(
    const u16* __restrict__ X, const u16* __restrict__ W1b,
    const float* __restrict__ wbuf, u16* __restrict__ hmid)
{
    __shared__ __align__(16) u16 As[2][8192];   // 2 x 256x32 bf16
    __shared__ __align__(16) u16 Bs[2][8192];   // total 64 KB -> 2 blocks/CU
    floatx4 acc[8][4] = {};
    // nt-major XCD swizzle: XCD x owns nt in {16x..16x+15}, processed in two
    // sub-stripes of 8 -> concurrent B footprint 8 x 0.5MB = 4MB = one L2.
    // W1b panel becomes L2-resident per XCD instead of streaming 64MB.
    const int bid = blockIdx.x;
    const int x   = bid & 7;             // XCD (round-robin dispatch)
    const int j   = bid >> 3;            // 0..255 within XCD
    const int sub = j >> 7;              // 0/1 sub-stripe
    const int nt  = x * 16 + sub * 8 + (j & 7);   // 0..127
    const int mt  = (j >> 3) & 15;                // 0..15
    const int rowBase = mt * 256, colBase = nt * 256;
    const int e  = colBase >> 12;               // expert of this 256-col tile
    const int ic0 = colBase & (ID - 1);         // col base within expert

    gemm256_tile(X, W1b, HD, HD, HD, rowBase, colBase,
                 As[0], As[1], Bs[0], Bs[1], acc);

    u16* hm = hmid + (size_t)e * NTOK * ID;
    const int t = threadIdx.x, w = t >> 6, lane = t & 63;
    const int wm = w & 1, wn = w >> 1, quad = lane >> 4, l15 = lane & 15;
#pragma unroll
    for (int mi = 0; mi < 8; ++mi)
#pragma unroll
        for (int r = 0; r < 4; ++r) {
            const int row = rowBase + wm * 128 + mi * 16 + quad * 4 + r;
            const float wv = wbuf[e * NTOK + row];
#pragma unroll
            for (int ni = 0; ni < 4; ++ni) {
                const int ic = ic0 + wn * 64 + ni * 16 + l15;
                hm[(size_t)row * ID + ic] =
                    f2bf(gelu_fast(acc[mi][ni][r]) * wv);
            }
        }
}

// ------- GEMM2 (one expert per z): slice[z] = hmid_z @ W2_z^T -------------
// z=8 -> grid 512 = 2 blocks/CU. Slices 0-3 alias wbuf/Xb/W1b (dead after
// gemm1); 4-7 follow hmid. hmid_z is contiguous (N x ID) -> ldA = ID.
__global__ __launch_bounds__(512, 2) void gemm2_kernel(
    const u16* __restrict__ hmid, const u16* __restrict__ W2b,
    float* __restrict__ acclo, float* __restrict__ acchi)
{
    __shared__ __align__(16) u16 As[2][8192];
    __shared__ __align__(16) u16 Bs[2][8192];
    floatx4 acc[8][4] = {};
    // 512 blocks (512 % 8 == 0): XCD x -> expert z=x; the 4 nt-blocks of one
    // (z,mt) run on that XCD -> hmid row-panel + W2 panel L2 reuse
    const int bid = blockIdx.x;
    const int swz = (bid & 7) * 64 + (bid >> 3);
    const int z = swz >> 6, mt = (swz >> 2) & 15, nt = swz & 3;
    const int rowBase = mt * 256, colBase = nt * 256;

    gemm256_tile(hmid + (size_t)z * NTOK * ID, W2b + (size_t)z * HD * ID,
                 ID, ID, ID, rowBase, colBase,
                 As[0], As[1], Bs[0], Bs[1], acc);

    const size_t NH = (size_t)NTOK * HD;
    float* accs = (z < 4) ? (acclo + (size_t)z * NH)
                          : (acchi + (size_t)(z - 4) * NH);
    const int t = threadIdx.x, w = t >> 6, lane = t & 63;
    const int wm = w & 1, wn = w >> 1, quad = lane >> 4, l15 = lane & 15;
#pragma unroll
    for (int mi = 0; mi < 8; ++mi)
#pragma unroll
        for (int r = 0; r < 4; ++r) {
            const int row = rowBase + wm * 128 + mi * 16 + quad * 4 + r;
#pragma unroll
            for (int ni = 0; ni < 4; ++ni) {
                const int col = colBase + wn * 64 + ni * 16 + l15;
                accs[(size_t)row * HD + col] = acc[mi][ni][r];
            }
        }
}

// ---------------- finalize: out = sum of 8 slices (fp32) ------------------
__global__ __launch_bounds__(256) void finalize_kernel(
    const float* __restrict__ acclo, const float* __restrict__ acchi,
    float* __restrict__ out)
{
    const size_t NH = (size_t)NTOK * HD;
    const size_t i = ((size_t)blockIdx.x * 256 + threadIdx.x) * 4;
    float4 o = *(const float4*)(acclo + i);
#pragma unroll
    for (int z = 1; z < 4; ++z) {
        const float4 a = *(const float4*)(acclo + (size_t)z * NH + i);
        o.x += a.x; o.y += a.y; o.z += a.z; o.w += a.w;
    }
#pragma unroll
    for (int z = 0; z < 4; ++z) {
        const float4 a = *(const float4*)(acchi + (size_t)z * NH + i);
        o.x += a.x; o.y += a.y; o.z += a.z; o.w += a.w;
    }
    *(float4*)(out + i) = o;
}

extern "C" void kernel_launch(void* const* d_in, const int* in_sizes, int n_in,
                              void* d_out, int out_size, void* d_ws, size_t ws_size,
                              hipStream_t stream) {
    const float* x  = (const float*)d_in[0];   // (N, H) fp32
    const float* Wr = (const float*)d_in[1];   // (E, H) fp32
    const float* W1 = (const float*)d_in[2];   // (E, I, H) fp32
    const float* W2 = (const float*)d_in[3];   // (E, H, I) fp32
    float* out = (float*)d_out;                // (N, H) fp32

    // ws layout (bytes):
    //   wbuf   @ 0        : E*N f32   = 128 KB   } dead after gemm1 ->
    //   Xb     @ 128K     : N*H bf16  = 8 MB     } aliased by acclo
    //   W1b    @ +8M      : E*I*H bf16= 64 MB    } (slices 0-3, 64 MB)
    //   W2b    @ 72.125M  : E*H*I bf16= 64 MB
    //   hmid   @ 136.125M : E*N*I bf16= 256 MB  (expert-contiguous)
    //   acchi  @ 392.125M : 4*N*H f32 = 64 MB  (slices 4-7)
    const size_t MB = 1024 * 1024;
    char* ws = (char*)d_ws;
    float* wbuf   = (float*)ws;
    u16*   Xb     = (u16*)(ws + 131072);
    u16*   W1b    = (u16*)(ws + 131072 + 8 * MB);
    u16*   W2b    = (u16*)(ws + 131072 + 72 * MB);
    u16*   hmid   = (u16*)(ws + 131072 + 136 * MB);
    float* acclo  = (float*)ws;                       // aliases wbuf/Xb/W1b
    float* acchi  = (float*)(ws + 131072 + 392 * MB);
    if (ws_size < 131072 + 456 * MB) return;   // fail loudly rather than corrupt

    convert_kernel<<<dim3((NTOK * HD) / 2048), 256, 0, stream>>>(x, Xb);
    convert2_kernel<<<dim3(2 * (NE * ID * HD) / 2048), 256, 0, stream>>>(
        W1, W1b, W2, W2b, (NE * ID * HD) / 2048);
    router_kernel<<<dim3(NTOK / 4), 256, 0, stream>>>(x, Wr, wbuf);

    gemm1_kernel<<<dim3(NE * ID / 256 * (NTOK / 256)), 512, 0, stream>>>(
        Xb, W1b, wbuf, hmid);
    gemm2_kernel<<<dim3((NTOK / 256) * (HD / 256) * 8), 512, 0, stream>>>(
        hmid, W2b, acclo, acchi);
    finalize_kernel<<<dim3(NTOK * HD / 1024), 256, 0, stream>>>(
        acclo, acchi, out);
}